// Round 1
// 154.301 us; speedup vs baseline: 1.0528x; 1.0528x over previous
//
#include <hip/hip_runtime.h>

// Problem constants (fixed by setup_inputs): B=4,T=32,H=224,W=224,C=3
namespace {
constexpr int B_ = 4, T_ = 32, H_ = 224, W_ = 224;
constexpr int HW_ = H_ * W_;              // 50176 pixels per (b,t) slice
constexpr int NPIX_ = B_ * T_ * HW_;      // 6422528
constexpr int N1_ = 79;                   // int(6422528*0.2*0.8 // 13005)
constexpr int N2_ = 9;                    // int(6422528*0.2*0.1 // 13005)
constexpr int NBOX_RW_ = N1_ + N2_;       // 88 boxes affect pixel output
constexpr int NBOX_M_  = N1_ + 2 * N2_;   // 97 boxes affect M
constexpr int HALF_T = 2, HALF_HW = 25;
constexpr int F4_TOTAL_ = NPIX_ * 3 / 4;  // 4816896 float4s
constexpr int ABLK_ = F4_TOTAL_ / 256;    // 18816 blocks, 1 float4/thread
constexpr int BPS_ = 147;                 // blocks per slice: 150528 floats / 1024
}

typedef float floatx4 __attribute__((ext_vector_type(4)));

// Single fused kernel. Key geometry: each block's 1024 floats lie entirely
// within one (b,t) slice (147 blocks/slice exactly), so each block can
// filter the 97 boxes itself (coalesced L2-hot loads), compact the rects
// that intersect its 2-3 h-rows into LDS, and test its two pixels directly.
// No gmask workspace, no serial build kernel. The streaming float4 load is
// issued before the filter so HBM latency hides under setup.
// Order semantics preserved: R2 wins over R1 (values within a class are
// identical so compaction order is irrelevant); exclusive upper bounds use
// size-1 exactly as the reference.
__global__ __launch_bounds__(256) void fused_mask(
    const floatx4* __restrict__ frames4, const float* __restrict__ frames,
    const float* __restrict__ mtok,
    const int* __restrict__ bb, const int* __restrict__ tt,
    const int* __restrict__ hh, const int* __restrict__ ww,
    const int* __restrict__ rb, const int* __restrict__ rt,
    const int* __restrict__ rh, const int* __restrict__ rw,
    floatx4* __restrict__ out4, float* __restrict__ Mout)
{
    const int tid = threadIdx.x;
    const unsigned g4 = blockIdx.x * 256u + tid;

    // Issue the streaming load first; everything below hides under it.
    floatx4 v = __builtin_nontemporal_load(&frames4[g4]);

    const int s  = blockIdx.x / BPS_;
    const int lb = blockIdx.x - s * BPS_;
    const int sb = s / T_, st = s - sb * T_;

    __shared__ int4 R1s[NBOX_RW_];
    __shared__ int4 R2s[N2_];
    __shared__ int c1, c2, cM;
    __shared__ float tok[6];   // [0..2]=mask_token, [3..5]=random_token

    if (tid == 0) { c1 = 0; c2 = 0; cM = 0; }
    __syncthreads();

    if (tid < NBOX_M_) {
        const int i = tid;
        int tlo = max(tt[i] - HALF_T, 0);
        int thi = min(tt[i] + HALF_T, T_ - 1);   // exclusive (ref uses size-1)
        if (bb[i] == sb && st >= tlo && st < thi) {
            cM = 1;                              // benign same-value race
            if (i < NBOX_RW_) {
                // this block's h-row range (2-3 rows)
                const int pf = (int)((1024u * blockIdx.x) / 3u) - s * HW_;
                const int pl = (int)((1024u * blockIdx.x + 1023u) / 3u) - s * HW_;
                const int hlo_blk = pf / W_, hhi_blk = pl / W_;
                int4 r;
                r.x = max(hh[i] - HALF_HW, 0);
                r.y = min(hh[i] + HALF_HW, H_ - 1);   // exclusive
                r.z = max(ww[i] - HALF_HW, 0);
                r.w = min(ww[i] + HALF_HW, W_ - 1);   // exclusive
                if (r.x <= hhi_blk && r.y > hlo_blk) {
                    if (i < N1_) R1s[atomicAdd(&c1, 1)] = r;
                    else         R2s[atomicAdd(&c2, 1)] = r;
                }
            }
        }
    } else if (tid == 128) {
        tok[0] = mtok[0]; tok[1] = mtok[1]; tok[2] = mtok[2];
        long idx = (((long)rb[0] * T_ + rt[0]) * H_ + rh[0]) * W_ + rw[0];
        tok[3] = frames[idx * 3 + 0];
        tok[4] = frames[idx * 3 + 1];
        tok[5] = frames[idx * 3 + 2];
    }
    __syncthreads();

    if (lb == 0 && tid == 0) Mout[s] = cM ? 1.0f : 0.0f;

    const int n1 = c1, n2 = c2;
    if (n1 | n2) {
        // this thread's 4 floats span pixels m and m+1; slot j holds
        // component (ph+j)%3 of pixel m + (ph+j)/3
        const unsigned q  = __umulhi(g4, 0xAAAAAAABu) >> 1;   // g4 / 3
        const unsigned ph = g4 - 3u * q;
        const unsigned m  = (4u * g4 - ph) * 0xAAAAAAABu;     // exact /3
        const int lpA = (int)m - s * HW_;
        const int hA = lpA / W_, wA = lpA - hA * W_;
        const int lpB = lpA + 1;
        const int hB = lpB / W_, wB = lpB - hB * W_;
        int in1a = 0, in1b = 0, in2a = 0, in2b = 0;
        for (int j = 0; j < n1; ++j) {
            int4 r = R1s[j];
            in1a |= (hA >= r.x) & (hA < r.y) & (wA >= r.z) & (wA < r.w);
            in1b |= (hB >= r.x) & (hB < r.y) & (wB >= r.z) & (wB < r.w);
        }
        for (int j = 0; j < n2; ++j) {
            int4 r = R2s[j];
            in2a |= (hA >= r.x) & (hA < r.y) & (wA >= r.z) & (wA < r.w);
            in2b |= (hB >= r.x) & (hB < r.y) & (wB >= r.z) & (wB < r.w);
        }
        if (in1a | in1b | in2a | in2b) {
            float m0 = tok[0], m1 = tok[1], m2 = tok[2];
            float r0 = tok[3], r1 = tok[4], r2 = tok[5];
            // rotated tokens: slot j holds component (ph+j)%3 (slot 3 == slot 0)
            float a0 = ph == 0 ? m0 : (ph == 1 ? m1 : m2);
            float a1 = ph == 0 ? m1 : (ph == 1 ? m2 : m0);
            float a2 = ph == 0 ? m2 : (ph == 1 ? m0 : m1);
            float b0 = ph == 0 ? r0 : (ph == 1 ? r1 : r2);
            float b1 = ph == 0 ? r1 : (ph == 1 ? r2 : r0);
            float b2 = ph == 0 ? r2 : (ph == 1 ? r0 : r1);
            const unsigned d1 = (ph + 1) / 3, d2 = (ph + 2) / 3;
            int i1y = d1 ? in1b : in1a, i2y = d1 ? in2b : in2a;
            int i1z = d2 ? in1b : in1a, i2z = d2 ? in2b : in2a;
            v.x = in2a ? b0 : (in1a ? a0 : v.x);
            v.y = i2y  ? b1 : (i1y  ? a1 : v.y);
            v.z = i2z  ? b2 : (i1z  ? a2 : v.z);
            v.w = in2b ? b0 : (in1b ? a0 : v.w);
        }
    }

    __builtin_nontemporal_store(v, &out4[g4]);
}

extern "C" void kernel_launch(void* const* d_in, const int* in_sizes, int n_in,
                              void* d_out, int out_size, void* d_ws, size_t ws_size,
                              hipStream_t stream)
{
    const float* frames = (const float*)d_in[0];
    const float* mtok   = (const float*)d_in[1];
    const int* b  = (const int*)d_in[2];
    const int* t  = (const int*)d_in[3];
    const int* h  = (const int*)d_in[4];
    const int* w  = (const int*)d_in[5];
    const int* rb = (const int*)d_in[6];
    const int* rt = (const int*)d_in[7];
    const int* rh = (const int*)d_in[8];
    const int* rw = (const int*)d_in[9];

    float* out_frames = (float*)d_out;
    float* out_M      = out_frames + (long)NPIX_ * 3;   // (B,T) flags as floats

    fused_mask<<<ABLK_, 256, 0, stream>>>((const floatx4*)frames, frames, mtok,
                                          b, t, h, w, rb, rt, rh, rw,
                                          (floatx4*)out_frames, out_M);
}

// Round 2
// 153.228 us; speedup vs baseline: 1.0602x; 1.0070x over previous
//
#include <hip/hip_runtime.h>

// Problem constants (fixed by setup_inputs): B=4,T=32,H=224,W=224,C=3
namespace {
constexpr int B_ = 4, T_ = 32, H_ = 224, W_ = 224;
constexpr int HW_ = H_ * W_;              // 50176 pixels per (b,t) slice
constexpr int NPIX_ = B_ * T_ * HW_;      // 6422528
constexpr int N1_ = 79;                   // int(6422528*0.2*0.8 // 13005)
constexpr int N2_ = 9;                    // int(6422528*0.2*0.1 // 13005)
constexpr int NBOX_RW_ = N1_ + N2_;       // 88 boxes affect pixel output
constexpr int NBOX_M_  = N1_ + 2 * N2_;   // 97 boxes affect M
constexpr int HALF_T = 2, HALF_HW = 25;
constexpr int F4_TOTAL_ = NPIX_ * 3 / 4;  // 4816896 float4s
constexpr int ABLK_ = F4_TOTAL_ / 256;    // 18816 blocks, 1 float4/thread
constexpr int BPS_ = 147;                 // blocks per slice: 150528 floats / 1024
}

typedef float floatx4 __attribute__((ext_vector_type(4)));

// Single fused kernel, v2: mask-first, conditional load.
// Each block's 1024 floats lie entirely within one (b,t) slice (147
// blocks/slice exactly). The block filters the 97 boxes (coalesced L2-hot
// loads), compacts rects intersecting its 2-3 h-rows into LDS, then each
// thread tests its two pixels. Threads whose BOTH pixels are masked by
// R1|R2 never read frames (all 4 slots get token values) — saves ~13% of
// the input fetch since box rows are 600 B contiguous segments.
// Blocks with no applicable rects take a uniform load->store fast path.
// Order semantics preserved: R2 wins over R1; exclusive upper bounds use
// size-1 exactly as the reference.
__global__ __launch_bounds__(256) void fused_mask(
    const floatx4* __restrict__ frames4, const float* __restrict__ frames,
    const float* __restrict__ mtok,
    const int* __restrict__ bb, const int* __restrict__ tt,
    const int* __restrict__ hh, const int* __restrict__ ww,
    const int* __restrict__ rb, const int* __restrict__ rt,
    const int* __restrict__ rh, const int* __restrict__ rw,
    floatx4* __restrict__ out4, float* __restrict__ Mout)
{
    const int tid = threadIdx.x;
    const unsigned g4 = blockIdx.x * 256u + tid;

    const int s  = blockIdx.x / BPS_;
    const int lb = blockIdx.x - s * BPS_;
    const int sb = s / T_, st = s - sb * T_;

    __shared__ int4 R1s[NBOX_RW_];
    __shared__ int4 R2s[N2_];
    __shared__ int c1, c2, cM;
    __shared__ float tok[6];   // [0..2]=mask_token, [3..5]=random_token

    if (tid == 0) { c1 = 0; c2 = 0; cM = 0; }
    __syncthreads();

    if (tid < NBOX_M_) {
        const int i = tid;
        int tlo = max(tt[i] - HALF_T, 0);
        int thi = min(tt[i] + HALF_T, T_ - 1);   // exclusive (ref uses size-1)
        if (bb[i] == sb && st >= tlo && st < thi) {
            cM = 1;                              // benign same-value race
            if (i < NBOX_RW_) {
                // this block's h-row range (2-3 rows)
                const int pf = (int)((1024u * blockIdx.x) / 3u) - s * HW_;
                const int pl = (int)((1024u * blockIdx.x + 1023u) / 3u) - s * HW_;
                const int hlo_blk = pf / W_, hhi_blk = pl / W_;
                int4 r;
                r.x = max(hh[i] - HALF_HW, 0);
                r.y = min(hh[i] + HALF_HW, H_ - 1);   // exclusive
                r.z = max(ww[i] - HALF_HW, 0);
                r.w = min(ww[i] + HALF_HW, W_ - 1);   // exclusive
                if (r.x <= hhi_blk && r.y > hlo_blk) {
                    if (i < N1_) R1s[atomicAdd(&c1, 1)] = r;
                    else         R2s[atomicAdd(&c2, 1)] = r;
                }
            }
        }
    } else if (tid == 128) {
        tok[0] = mtok[0]; tok[1] = mtok[1]; tok[2] = mtok[2];
        long idx = (((long)rb[0] * T_ + rt[0]) * H_ + rh[0]) * W_ + rw[0];
        tok[3] = frames[idx * 3 + 0];
        tok[4] = frames[idx * 3 + 1];
        tok[5] = frames[idx * 3 + 2];
    }
    __syncthreads();

    if (lb == 0 && tid == 0) Mout[s] = cM ? 1.0f : 0.0f;

    const int n1 = c1, n2 = c2;

    if ((n1 | n2) == 0) {
        // uniform fast path (vast majority of blocks): pure stream
        floatx4 v = __builtin_nontemporal_load(&frames4[g4]);
        __builtin_nontemporal_store(v, &out4[g4]);
        return;
    }

    // this thread's 4 floats span pixels m and m+1; slot j holds
    // component (ph+j)%3 of pixel m + (ph+j)/3
    const unsigned q  = __umulhi(g4, 0xAAAAAAABu) >> 1;   // g4 / 3
    const unsigned ph = g4 - 3u * q;
    const unsigned m  = (4u * g4 - ph) * 0xAAAAAAABu;     // exact /3
    const int lpA = (int)m - s * HW_;
    const int hA = lpA / W_, wA = lpA - hA * W_;
    int hB = hA, wB = wA + 1;
    if (wB == W_) { wB = 0; hB = hA + 1; }

    int in1a = 0, in1b = 0, in2a = 0, in2b = 0;
    for (int j = 0; j < n1; ++j) {
        int4 r = R1s[j];
        in1a |= (hA >= r.x) & (hA < r.y) & (wA >= r.z) & (wA < r.w);
        in1b |= (hB >= r.x) & (hB < r.y) & (wB >= r.z) & (wB < r.w);
    }
    for (int j = 0; j < n2; ++j) {
        int4 r = R2s[j];
        in2a |= (hA >= r.x) & (hA < r.y) & (wA >= r.z) & (wA < r.w);
        in2b |= (hB >= r.x) & (hB < r.y) & (wB >= r.z) & (wB < r.w);
    }
    const int ina = in1a | in2a, inb = in1b | in2b;

    floatx4 v = {0.f, 0.f, 0.f, 0.f};
    if (!(ina & inb))                     // some slot survives -> need frames
        v = __builtin_nontemporal_load(&frames4[g4]);

    if (ina | inb) {
        float m0 = tok[0], m1 = tok[1], m2 = tok[2];
        float r0 = tok[3], r1 = tok[4], r2 = tok[5];
        // rotated tokens: slot j holds component (ph+j)%3 (slot 3 == slot 0)
        float a0 = ph == 0 ? m0 : (ph == 1 ? m1 : m2);
        float a1 = ph == 0 ? m1 : (ph == 1 ? m2 : m0);
        float a2 = ph == 0 ? m2 : (ph == 1 ? m0 : m1);
        float b0 = ph == 0 ? r0 : (ph == 1 ? r1 : r2);
        float b1 = ph == 0 ? r1 : (ph == 1 ? r2 : r0);
        float b2 = ph == 0 ? r2 : (ph == 1 ? r0 : r1);
        const unsigned d1 = (ph + 1) / 3, d2 = (ph + 2) / 3;
        int i1y = d1 ? in1b : in1a, i2y = d1 ? in2b : in2a;
        int i1z = d2 ? in1b : in1a, i2z = d2 ? in2b : in2a;
        v.x = in2a ? b0 : (in1a ? a0 : v.x);
        v.y = i2y  ? b1 : (i1y  ? a1 : v.y);
        v.z = i2z  ? b2 : (i1z  ? a2 : v.z);
        v.w = in2b ? b0 : (in1b ? a0 : v.w);
    }

    __builtin_nontemporal_store(v, &out4[g4]);
}

extern "C" void kernel_launch(void* const* d_in, const int* in_sizes, int n_in,
                              void* d_out, int out_size, void* d_ws, size_t ws_size,
                              hipStream_t stream)
{
    const float* frames = (const float*)d_in[0];
    const float* mtok   = (const float*)d_in[1];
    const int* b  = (const int*)d_in[2];
    const int* t  = (const int*)d_in[3];
    const int* h  = (const int*)d_in[4];
    const int* w  = (const int*)d_in[5];
    const int* rb = (const int*)d_in[6];
    const int* rt = (const int*)d_in[7];
    const int* rh = (const int*)d_in[8];
    const int* rw = (const int*)d_in[9];

    float* out_frames = (float*)d_out;
    float* out_M      = out_frames + (long)NPIX_ * 3;   // (B,T) flags as floats

    fused_mask<<<ABLK_, 256, 0, stream>>>((const floatx4*)frames, frames, mtok,
                                          b, t, h, w, rb, rt, rh, rw,
                                          (floatx4*)out_frames, out_M);
}